// Round 4
// baseline (1283.067 us; speedup 1.0000x reference)
//
#include <hip/hip_runtime.h>

#define B_   16
#define CIN  256
#define T_   8192
#define D_   64
#define KK   512

typedef __attribute__((ext_vector_type(8)))  short short8v;
typedef __attribute__((ext_vector_type(16))) float f32x16;

__device__ __forceinline__ unsigned f2bf(float f) {          // RTNE float->bf16
    union { float f; unsigned u; } v; v.f = f;
    unsigned r = v.u + 0x7fffu + ((v.u >> 16) & 1u);
    return r >> 16;
}
__device__ __forceinline__ float bflo(unsigned u) {
    union { unsigned u; float f; } v; v.u = u << 16; return v.f;
}
__device__ __forceinline__ float bfhi(unsigned u) {
    union { unsigned u; float f; } v; v.u = u & 0xffff0000u; return v.f;
}

// ---------------------------------------------------------------------------
// Kernel 1: z[bt][d] (bf16) = sum_c x[b][c][t] * W[d][c] + bias[d]
// 512 blocks x 512 thr; BT=256 t per block. bf16 LDS operands (48 KB total).
// Per thread: 4t x 8d fp32 accumulators.
// ---------------------------------------------------------------------------
__global__ __launch_bounds__(512, 4) void zproj_kernel(
    const float* __restrict__ x, const float* __restrict__ W,
    const float* __restrict__ bias, unsigned short* __restrict__ z)
{
    __shared__ unsigned short Wt[CIN * 64];     // [c][d] bf16, slot-swizzled, 32 KB
    __shared__ unsigned short xs[2][16 * 256];  // [c][t] bf16, 8 KB each

    const int tid = threadIdx.x;
    const int bid = blockIdx.x;
    const int b   = bid >> 5;
    const int t0  = (bid & 31) << 8;            // *256

    // ---- stage W (transposed, bf16, swizzled). thread: c=tid>>1, 32 d's.
    {
        const int c  = tid >> 1;
        const int dh = (tid & 1) << 5;          // 0 or 32
        float wv[32];
        #pragma unroll
        for (int i = 0; i < 32; ++i) wv[i] = W[(size_t)(dh + i) * CIN + c];
        uint4* wrow = (uint4*)Wt;               // 8 slots (16 B) per c-row
        #pragma unroll
        for (int s = 0; s < 4; ++s) {           // this thread's slots
            uint4 pk;
            pk.x = f2bf(wv[s*8+0]) | (f2bf(wv[s*8+1]) << 16);
            pk.y = f2bf(wv[s*8+2]) | (f2bf(wv[s*8+3]) << 16);
            pk.z = f2bf(wv[s*8+4]) | (f2bf(wv[s*8+5]) << 16);
            pk.w = f2bf(wv[s*8+6]) | (f2bf(wv[s*8+7]) << 16);
            const int slot = (dh >> 3) + s;     // d-slot 0..7
            wrow[c * 8 + (slot ^ (c & 7))] = pk;
        }
    }

    const int dg = (tid & 7) << 3;              // d base (0..56)
    const int tq = tid >> 3;                    // t quad id (0..63), t = 4*tq

    float acc[4][8];
    #pragma unroll
    for (int i = 0; i < 4; ++i)
        #pragma unroll
        for (int j = 0; j < 8; ++j) acc[i][j] = 0.f;

    const float* xb = x + ((size_t)b * CIN) * T_ + t0;

#define LOADX(dst, ch) do {                                                   \
        _Pragma("unroll")                                                     \
        for (int p = 0; p < 2; ++p) {                                         \
            int j_ = tid + (p << 9);                                          \
            dst[p] = *(const float4*)(xb + (size_t)((ch)*16 + (j_ >> 6)) * T_ \
                                      + ((j_ & 63) << 2));                    \
        }                                                                     \
    } while (0)

#define WRITEX(src, bsel) do {                                                \
        uint2* xw_ = (uint2*)xs[bsel];                                        \
        _Pragma("unroll")                                                     \
        for (int p = 0; p < 2; ++p) {                                         \
            int j_ = tid + (p << 9);                                          \
            uint2 pk_;                                                        \
            pk_.x = f2bf(src[p].x) | (f2bf(src[p].y) << 16);                  \
            pk_.y = f2bf(src[p].z) | (f2bf(src[p].w) << 16);                  \
            xw_[((j_ >> 6) << 6) + (j_ & 63)] = pk_;                          \
        }                                                                     \
    } while (0)

    float4 ra[2], rb[2];
    LOADX(ra, 0);
    WRITEX(ra, 0);
    __syncthreads();

    #pragma unroll 1
    for (int ch = 0; ch < 16; ++ch) {
        if (ch + 1 < 16) LOADX(rb, ch + 1);
        const uint2* xr = (const uint2*)xs[ch & 1];
        #pragma unroll
        for (int cc = 0; cc < 16; ++cc) {
            const int cg = ch * 16 + cc;
            uint4 wq = ((const uint4*)Wt)[cg * 8 + ((tid & 7) ^ (cg & 7))];
            uint2 xq = xr[(cc << 6) + tq];
            float wf[8] = { bflo(wq.x), bfhi(wq.x), bflo(wq.y), bfhi(wq.y),
                            bflo(wq.z), bfhi(wq.z), bflo(wq.w), bfhi(wq.w) };
            float xf[4] = { bflo(xq.x), bfhi(xq.x), bflo(xq.y), bfhi(xq.y) };
            #pragma unroll
            for (int i = 0; i < 4; ++i)
                #pragma unroll
                for (int j = 0; j < 8; ++j)
                    acc[i][j] = fmaf(xf[i], wf[j], acc[i][j]);
        }
        __syncthreads();
        if (ch + 1 < 16) {
            WRITEX(rb, (ch + 1) & 1);
            ra[0] = rb[0]; ra[1] = rb[1];
        }
        __syncthreads();
    }

    // ---- epilogue: +bias, pack bf16, store
    float bv[8];
    #pragma unroll
    for (int j = 0; j < 8; ++j) bv[j] = bias[dg + j];
    #pragma unroll
    for (int i = 0; i < 4; ++i) {
        uint4 pk;
        float v0 = acc[i][0] + bv[0], v1 = acc[i][1] + bv[1];
        float v2 = acc[i][2] + bv[2], v3 = acc[i][3] + bv[3];
        float v4 = acc[i][4] + bv[4], v5 = acc[i][5] + bv[5];
        float v6 = acc[i][6] + bv[6], v7 = acc[i][7] + bv[7];
        pk.x = f2bf(v0) | (f2bf(v1) << 16);
        pk.y = f2bf(v2) | (f2bf(v3) << 16);
        pk.z = f2bf(v4) | (f2bf(v5) << 16);
        pk.w = f2bf(v6) | (f2bf(v7) << 16);
        *(uint4*)(z + ((size_t)(bid * 256 + tq * 4 + i)) * 64 + dg) = pk;
    }
#undef LOADX
#undef WRITEX
}

// ---------------------------------------------------------------------------
// Kernel 2: out[t][0..1] = ||z_t||^2 + min_k( ||e_k||^2 - 2 z_t.e_k )
// via bf16 MFMA 32x32x16. 256 blocks x 512 thr; BT=512 t per block.
// 8 waves = 4 t-groups (128 t) x 2 n-groups (256 n).
// ---------------------------------------------------------------------------
__global__ __launch_bounds__(512, 2) void vq_kernel(
    const unsigned short* __restrict__ z, const float* __restrict__ cb,
    float* __restrict__ out)
{
    __shared__ char smem[65536 + 4096];
    unsigned short* cbb = (unsigned short*)smem;   // [512][64] bf16 swizzled
    float* minb = (float*)smem;                    // [512][32] f32 swizzled (alias)
    float* znb  = (float*)(smem + 65536);          // [512]
    float* n2b  = (float*)(smem + 65536 + 2048);   // [512]

    const int tid  = threadIdx.x;
    const int lane = tid & 63;
    const int w    = tid >> 6;
    const int l31  = lane & 31;
    const int lh   = lane >> 5;        // 0/1
    const int tg   = w >> 1;           // t-group 0..3
    const int ng   = w & 1;            // n-group 0/1

    // ---- stage codebook row n=tid (bf16, slot-swizzled) + n2
    {
        const float* cr = cb + (size_t)tid * 64;
        uint4* crow = (uint4*)cbb;
        float s = 0.f;
        #pragma unroll
        for (int sl = 0; sl < 8; ++sl) {
            float4 a = *(const float4*)(cr + sl * 8);
            float4 b = *(const float4*)(cr + sl * 8 + 4);
            s = fmaf(a.x, a.x, s); s = fmaf(a.y, a.y, s);
            s = fmaf(a.z, a.z, s); s = fmaf(a.w, a.w, s);
            s = fmaf(b.x, b.x, s); s = fmaf(b.y, b.y, s);
            s = fmaf(b.z, b.z, s); s = fmaf(b.w, b.w, s);
            uint4 pk;
            pk.x = f2bf(a.x) | (f2bf(a.y) << 16);
            pk.y = f2bf(a.z) | (f2bf(a.w) << 16);
            pk.z = f2bf(b.x) | (f2bf(b.y) << 16);
            pk.w = f2bf(b.z) | (f2bf(b.w) << 16);
            crow[tid * 8 + (sl ^ (tid & 7))] = pk;
        }
        n2b[tid] = s;
    }

    // ---- A-frags (z rows) from global + ||z||^2
    const size_t tbase = (size_t)blockIdx.x * 512 + tg * 128;
    short8v a[4][4];
    #pragma unroll
    for (int tt = 0; tt < 4; ++tt) {
        const unsigned short* zr = z + (tbase + tt * 32 + l31) * 64;
        float p = 0.f;
        #pragma unroll
        for (int ks = 0; ks < 4; ++ks) {
            uint4 v = *(const uint4*)(zr + ks * 16 + lh * 8);
            a[tt][ks] = __builtin_bit_cast(short8v, v);
            float e0 = bflo(v.x), e1 = bfhi(v.x), e2 = bflo(v.y), e3 = bfhi(v.y);
            float e4 = bflo(v.z), e5 = bfhi(v.z), e6 = bflo(v.w), e7 = bfhi(v.w);
            p = fmaf(e0, e0, p); p = fmaf(e1, e1, p);
            p = fmaf(e2, e2, p); p = fmaf(e3, e3, p);
            p = fmaf(e4, e4, p); p = fmaf(e5, e5, p);
            p = fmaf(e6, e6, p); p = fmaf(e7, e7, p);
        }
        p += __shfl_xor(p, 32);
        if (ng == 0 && lh == 0)
            znb[tg * 128 + tt * 32 + l31] = p;
    }
    __syncthreads();

    // ---- main loop: 8 n-tiles of 32 per wave
    float rmin[4][16];
    #pragma unroll
    for (int tt = 0; tt < 4; ++tt)
        #pragma unroll
        for (int r = 0; r < 16; ++r) rmin[tt][r] = 3.0e38f;

    #pragma unroll 1
    for (int nt = 0; nt < 8; ++nt) {
        const int n = ng * 256 + nt * 32 + l31;
        const float n2v = n2b[n];
        short8v bfr[4];
        #pragma unroll
        for (int ks = 0; ks < 4; ++ks) {
            const int slot = 2 * ks + lh;
            uint4 v = ((const uint4*)cbb)[n * 8 + (slot ^ (n & 7))];
            bfr[ks] = __builtin_bit_cast(short8v, v);
        }
        #pragma unroll
        for (int tt = 0; tt < 4; ++tt) {
            f32x16 acc = (f32x16)(0.0f);
            acc = __builtin_amdgcn_mfma_f32_32x32x16_bf16(a[tt][0], bfr[0], acc, 0, 0, 0);
            acc = __builtin_amdgcn_mfma_f32_32x32x16_bf16(a[tt][1], bfr[1], acc, 0, 0, 0);
            acc = __builtin_amdgcn_mfma_f32_32x32x16_bf16(a[tt][2], bfr[2], acc, 0, 0, 0);
            acc = __builtin_amdgcn_mfma_f32_32x32x16_bf16(a[tt][3], bfr[3], acc, 0, 0, 0);
            #pragma unroll
            for (int r = 0; r < 16; ++r)
                rmin[tt][r] = fminf(rmin[tt][r], fmaf(-2.f, acc[r], n2v));
        }
    }
    __syncthreads();          // cbb dead; minb aliases it

    // ---- combine n-groups into minb[t][col], swizzled 16B slots
#define MIDX(t_, c_) ((t_) * 32 + ((((c_) >> 2) ^ ((t_) & 7)) << 2) + ((c_) & 3))
    if (ng == 0) {
        #pragma unroll
        for (int tt = 0; tt < 4; ++tt)
            #pragma unroll
            for (int r = 0; r < 16; ++r) {
                int tl = tg * 128 + tt * 32 + (r & 3) + 8 * (r >> 2) + 4 * lh;
                minb[MIDX(tl, l31)] = rmin[tt][r];
            }
    }
    __syncthreads();
    if (ng == 1) {
        #pragma unroll
        for (int tt = 0; tt < 4; ++tt)
            #pragma unroll
            for (int r = 0; r < 16; ++r) {
                int tl = tg * 128 + tt * 32 + (r & 3) + 8 * (r >> 2) + 4 * lh;
                int ix = MIDX(tl, l31);
                minb[ix] = fminf(minb[ix], rmin[tt][r]);
            }
    }
    __syncthreads();
#undef MIDX

    // ---- final: thread t=tid reduces 32 cols, adds ||z||^2, writes both outs
    {
        float m = 3.0e38f;
        #pragma unroll
        for (int sl = 0; sl < 8; ++sl) {
            float4 v = *(const float4*)&minb[tid * 32 + ((sl ^ (tid & 7)) << 2)];
            m = fminf(m, fminf(fminf(v.x, v.y), fminf(v.z, v.w)));
        }
        float r = znb[tid] + m;
        float2 o; o.x = r; o.y = r;
        *(float2*)(out + ((size_t)blockIdx.x * 512 + tid) * 2) = o;
    }
}

// ---------------------------------------------------------------------------
extern "C" void kernel_launch(void* const* d_in, const int* in_sizes, int n_in,
                              void* d_out, int out_size, void* d_ws, size_t ws_size,
                              hipStream_t stream) {
    const float* x    = (const float*)d_in[0];
    const float* W    = (const float*)d_in[1];
    const float* bias = (const float*)d_in[2];
    const float* cb   = (const float*)d_in[3];
    float* out = (float*)d_out;

    unsigned short* z = (unsigned short*)d_ws;   // B*T*D bf16 = 16.8 MB

    zproj_kernel<<<512, 512, 0, stream>>>(x, W, bias, z);
    vq_kernel<<<256, 512, 0, stream>>>(z, cb, out);
}

// Round 5
// 271.538 us; speedup vs baseline: 4.7252x; 4.7252x over previous
//
#include <hip/hip_runtime.h>

#define B_   16
#define CIN  256
#define T_   8192
#define D_   64
#define KK   512

typedef __attribute__((ext_vector_type(8)))  short short8v;
typedef __attribute__((ext_vector_type(16))) float f32x16;

__device__ __forceinline__ unsigned f2bf(float f) {          // RTNE float->bf16
    union { float f; unsigned u; } v; v.f = f;
    unsigned r = v.u + 0x7fffu + ((v.u >> 16) & 1u);
    return r >> 16;
}
__device__ __forceinline__ float bflo(unsigned u) {
    union { unsigned u; float f; } v; v.u = u << 16; return v.f;
}
__device__ __forceinline__ float bfhi(unsigned u) {
    union { unsigned u; float f; } v; v.u = u & 0xffff0000u; return v.f;
}

// ---------------------------------------------------------------------------
// Kernel 1: z[bt][d] (bf16) = sum_c x[b][c][t] * W[d][c] + bias[d]
// 512 blocks x 512 thr; BT=256 t per block. bf16 LDS operands (48 KB total).
// Per thread: 4t x 8d fp32 accumulators.
// launch_bounds(512,2): VGPR cap 256 — (512,4) capped at 64 and spilled
// 5 GB/dispatch of scratch traffic to HBM (round-4 counters).
// ---------------------------------------------------------------------------
__global__ __launch_bounds__(512, 2) void zproj_kernel(
    const float* __restrict__ x, const float* __restrict__ W,
    const float* __restrict__ bias, unsigned short* __restrict__ z)
{
    __shared__ unsigned short Wt[CIN * 64];     // [c][d] bf16, slot-swizzled, 32 KB
    __shared__ unsigned short xs[2][16 * 256];  // [c][t] bf16, 8 KB each

    const int tid = threadIdx.x;
    const int bid = blockIdx.x;
    const int b   = bid >> 5;
    const int t0  = (bid & 31) << 8;            // *256

    // ---- stage W (transposed, bf16, swizzled). thread: c=tid>>1, 32 d's.
    {
        const int c  = tid >> 1;
        const int dh = (tid & 1) << 5;          // 0 or 32
        float wv[32];
        #pragma unroll
        for (int i = 0; i < 32; ++i) wv[i] = W[(size_t)(dh + i) * CIN + c];
        uint4* wrow = (uint4*)Wt;               // 8 slots (16 B) per c-row
        #pragma unroll
        for (int s = 0; s < 4; ++s) {           // this thread's slots
            uint4 pk;
            pk.x = f2bf(wv[s*8+0]) | (f2bf(wv[s*8+1]) << 16);
            pk.y = f2bf(wv[s*8+2]) | (f2bf(wv[s*8+3]) << 16);
            pk.z = f2bf(wv[s*8+4]) | (f2bf(wv[s*8+5]) << 16);
            pk.w = f2bf(wv[s*8+6]) | (f2bf(wv[s*8+7]) << 16);
            const int slot = (dh >> 3) + s;     // d-slot 0..7
            wrow[c * 8 + (slot ^ (c & 7))] = pk;
        }
    }

    const int dg = (tid & 7) << 3;              // d base (0..56)
    const int tq = tid >> 3;                    // t quad id (0..63), t = 4*tq

    float acc[4][8];
    #pragma unroll
    for (int i = 0; i < 4; ++i)
        #pragma unroll
        for (int j = 0; j < 8; ++j) acc[i][j] = 0.f;

    const float* xb = x + ((size_t)b * CIN) * T_ + t0;

#define LOADX(dst, ch) do {                                                   \
        _Pragma("unroll")                                                     \
        for (int p = 0; p < 2; ++p) {                                         \
            int j_ = tid + (p << 9);                                          \
            dst[p] = *(const float4*)(xb + (size_t)((ch)*16 + (j_ >> 6)) * T_ \
                                      + ((j_ & 63) << 2));                    \
        }                                                                     \
    } while (0)

#define WRITEX(src, bsel) do {                                                \
        uint2* xw_ = (uint2*)xs[bsel];                                        \
        _Pragma("unroll")                                                     \
        for (int p = 0; p < 2; ++p) {                                         \
            int j_ = tid + (p << 9);                                          \
            uint2 pk_;                                                        \
            pk_.x = f2bf(src[p].x) | (f2bf(src[p].y) << 16);                  \
            pk_.y = f2bf(src[p].z) | (f2bf(src[p].w) << 16);                  \
            xw_[((j_ >> 6) << 6) + (j_ & 63)] = pk_;                          \
        }                                                                     \
    } while (0)

    float4 ra[2], rb[2];
    LOADX(ra, 0);
    WRITEX(ra, 0);
    __syncthreads();

    #pragma unroll 1
    for (int ch = 0; ch < 16; ++ch) {
        if (ch + 1 < 16) LOADX(rb, ch + 1);
        const uint2* xr = (const uint2*)xs[ch & 1];
        #pragma unroll
        for (int cc = 0; cc < 16; ++cc) {
            const int cg = ch * 16 + cc;
            uint4 wq = ((const uint4*)Wt)[cg * 8 + ((tid & 7) ^ (cg & 7))];
            uint2 xq = xr[(cc << 6) + tq];
            float wf[8] = { bflo(wq.x), bfhi(wq.x), bflo(wq.y), bfhi(wq.y),
                            bflo(wq.z), bfhi(wq.z), bflo(wq.w), bfhi(wq.w) };
            float xf[4] = { bflo(xq.x), bfhi(xq.x), bflo(xq.y), bfhi(xq.y) };
            #pragma unroll
            for (int i = 0; i < 4; ++i)
                #pragma unroll
                for (int j = 0; j < 8; ++j)
                    acc[i][j] = fmaf(xf[i], wf[j], acc[i][j]);
        }
        __syncthreads();
        if (ch + 1 < 16) {
            WRITEX(rb, (ch + 1) & 1);
            ra[0] = rb[0]; ra[1] = rb[1];
        }
        __syncthreads();
    }

    // ---- epilogue: +bias, pack bf16, store
    float bv[8];
    #pragma unroll
    for (int j = 0; j < 8; ++j) bv[j] = bias[dg + j];
    #pragma unroll
    for (int i = 0; i < 4; ++i) {
        uint4 pk;
        float v0 = acc[i][0] + bv[0], v1 = acc[i][1] + bv[1];
        float v2 = acc[i][2] + bv[2], v3 = acc[i][3] + bv[3];
        float v4 = acc[i][4] + bv[4], v5 = acc[i][5] + bv[5];
        float v6 = acc[i][6] + bv[6], v7 = acc[i][7] + bv[7];
        pk.x = f2bf(v0) | (f2bf(v1) << 16);
        pk.y = f2bf(v2) | (f2bf(v3) << 16);
        pk.z = f2bf(v4) | (f2bf(v5) << 16);
        pk.w = f2bf(v6) | (f2bf(v7) << 16);
        *(uint4*)(z + ((size_t)(bid * 256 + tq * 4 + i)) * 64 + dg) = pk;
    }
#undef LOADX
#undef WRITEX
}

// ---------------------------------------------------------------------------
// Kernel 2: out[t][0..1] = ||z_t||^2 + min_k( ||e_k||^2 - 2 z_t.e_k )
// via bf16 MFMA 32x32x16. 256 blocks x 512 thr; BT=512 t per block.
// 8 waves = 4 t-groups (128 t) x 2 n-groups (256 n).
// (unchanged this round — next profile will expose its counters)
// ---------------------------------------------------------------------------
__global__ __launch_bounds__(512, 2) void vq_kernel(
    const unsigned short* __restrict__ z, const float* __restrict__ cb,
    float* __restrict__ out)
{
    __shared__ char smem[65536 + 4096];
    unsigned short* cbb = (unsigned short*)smem;   // [512][64] bf16 swizzled
    float* minb = (float*)smem;                    // [512][32] f32 swizzled (alias)
    float* znb  = (float*)(smem + 65536);          // [512]
    float* n2b  = (float*)(smem + 65536 + 2048);   // [512]

    const int tid  = threadIdx.x;
    const int lane = tid & 63;
    const int w    = tid >> 6;
    const int l31  = lane & 31;
    const int lh   = lane >> 5;        // 0/1
    const int tg   = w >> 1;           // t-group 0..3
    const int ng   = w & 1;            // n-group 0/1

    // ---- stage codebook row n=tid (bf16, slot-swizzled) + n2
    {
        const float* cr = cb + (size_t)tid * 64;
        uint4* crow = (uint4*)cbb;
        float s = 0.f;
        #pragma unroll
        for (int sl = 0; sl < 8; ++sl) {
            float4 a = *(const float4*)(cr + sl * 8);
            float4 b = *(const float4*)(cr + sl * 8 + 4);
            s = fmaf(a.x, a.x, s); s = fmaf(a.y, a.y, s);
            s = fmaf(a.z, a.z, s); s = fmaf(a.w, a.w, s);
            s = fmaf(b.x, b.x, s); s = fmaf(b.y, b.y, s);
            s = fmaf(b.z, b.z, s); s = fmaf(b.w, b.w, s);
            uint4 pk;
            pk.x = f2bf(a.x) | (f2bf(a.y) << 16);
            pk.y = f2bf(a.z) | (f2bf(a.w) << 16);
            pk.z = f2bf(b.x) | (f2bf(b.y) << 16);
            pk.w = f2bf(b.z) | (f2bf(b.w) << 16);
            crow[tid * 8 + (sl ^ (tid & 7))] = pk;
        }
        n2b[tid] = s;
    }

    // ---- A-frags (z rows) from global + ||z||^2
    const size_t tbase = (size_t)blockIdx.x * 512 + tg * 128;
    short8v a[4][4];
    #pragma unroll
    for (int tt = 0; tt < 4; ++tt) {
        const unsigned short* zr = z + (tbase + tt * 32 + l31) * 64;
        float p = 0.f;
        #pragma unroll
        for (int ks = 0; ks < 4; ++ks) {
            uint4 v = *(const uint4*)(zr + ks * 16 + lh * 8);
            a[tt][ks] = __builtin_bit_cast(short8v, v);
            float e0 = bflo(v.x), e1 = bfhi(v.x), e2 = bflo(v.y), e3 = bfhi(v.y);
            float e4 = bflo(v.z), e5 = bfhi(v.z), e6 = bflo(v.w), e7 = bfhi(v.w);
            p = fmaf(e0, e0, p); p = fmaf(e1, e1, p);
            p = fmaf(e2, e2, p); p = fmaf(e3, e3, p);
            p = fmaf(e4, e4, p); p = fmaf(e5, e5, p);
            p = fmaf(e6, e6, p); p = fmaf(e7, e7, p);
        }
        p += __shfl_xor(p, 32);
        if (ng == 0 && lh == 0)
            znb[tg * 128 + tt * 32 + l31] = p;
    }
    __syncthreads();

    // ---- main loop: 8 n-tiles of 32 per wave
    float rmin[4][16];
    #pragma unroll
    for (int tt = 0; tt < 4; ++tt)
        #pragma unroll
        for (int r = 0; r < 16; ++r) rmin[tt][r] = 3.0e38f;

    #pragma unroll 1
    for (int nt = 0; nt < 8; ++nt) {
        const int n = ng * 256 + nt * 32 + l31;
        const float n2v = n2b[n];
        short8v bfr[4];
        #pragma unroll
        for (int ks = 0; ks < 4; ++ks) {
            const int slot = 2 * ks + lh;
            uint4 v = ((const uint4*)cbb)[n * 8 + (slot ^ (n & 7))];
            bfr[ks] = __builtin_bit_cast(short8v, v);
        }
        #pragma unroll
        for (int tt = 0; tt < 4; ++tt) {
            f32x16 acc = (f32x16)(0.0f);
            acc = __builtin_amdgcn_mfma_f32_32x32x16_bf16(a[tt][0], bfr[0], acc, 0, 0, 0);
            acc = __builtin_amdgcn_mfma_f32_32x32x16_bf16(a[tt][1], bfr[1], acc, 0, 0, 0);
            acc = __builtin_amdgcn_mfma_f32_32x32x16_bf16(a[tt][2], bfr[2], acc, 0, 0, 0);
            acc = __builtin_amdgcn_mfma_f32_32x32x16_bf16(a[tt][3], bfr[3], acc, 0, 0, 0);
            #pragma unroll
            for (int r = 0; r < 16; ++r)
                rmin[tt][r] = fminf(rmin[tt][r], fmaf(-2.f, acc[r], n2v));
        }
    }
    __syncthreads();          // cbb dead; minb aliases it

    // ---- combine n-groups into minb[t][col], swizzled 16B slots
#define MIDX(t_, c_) ((t_) * 32 + ((((c_) >> 2) ^ ((t_) & 7)) << 2) + ((c_) & 3))
    if (ng == 0) {
        #pragma unroll
        for (int tt = 0; tt < 4; ++tt)
            #pragma unroll
            for (int r = 0; r < 16; ++r) {
                int tl = tg * 128 + tt * 32 + (r & 3) + 8 * (r >> 2) + 4 * lh;
                minb[MIDX(tl, l31)] = rmin[tt][r];
            }
    }
    __syncthreads();
    if (ng == 1) {
        #pragma unroll
        for (int tt = 0; tt < 4; ++tt)
            #pragma unroll
            for (int r = 0; r < 16; ++r) {
                int tl = tg * 128 + tt * 32 + (r & 3) + 8 * (r >> 2) + 4 * lh;
                int ix = MIDX(tl, l31);
                minb[ix] = fminf(minb[ix], rmin[tt][r]);
            }
    }
    __syncthreads();
#undef MIDX

    // ---- final: thread t=tid reduces 32 cols, adds ||z||^2, writes both outs
    {
        float m = 3.0e38f;
        #pragma unroll
        for (int sl = 0; sl < 8; ++sl) {
            float4 v = *(const float4*)&minb[tid * 32 + ((sl ^ (tid & 7)) << 2)];
            m = fminf(m, fminf(fminf(v.x, v.y), fminf(v.z, v.w)));
        }
        float r = znb[tid] + m;
        float2 o; o.x = r; o.y = r;
        *(float2*)(out + ((size_t)blockIdx.x * 512 + tid) * 2) = o;
    }
}

// ---------------------------------------------------------------------------
extern "C" void kernel_launch(void* const* d_in, const int* in_sizes, int n_in,
                              void* d_out, int out_size, void* d_ws, size_t ws_size,
                              hipStream_t stream) {
    const float* x    = (const float*)d_in[0];
    const float* W    = (const float*)d_in[1];
    const float* bias = (const float*)d_in[2];
    const float* cb   = (const float*)d_in[3];
    float* out = (float*)d_out;

    unsigned short* z = (unsigned short*)d_ws;   // B*T*D bf16 = 16.8 MB

    zproj_kernel<<<512, 512, 0, stream>>>(x, W, bias, z);
    vq_kernel<<<256, 512, 0, stream>>>(z, cb, out);
}

// Round 7
// 218.603 us; speedup vs baseline: 5.8694x; 1.2422x over previous
//
#include <hip/hip_runtime.h>

#define B_   16
#define CIN  256
#define T_   8192
#define D_   64
#define KK   512

typedef __attribute__((ext_vector_type(8)))  short short8v;
typedef __attribute__((ext_vector_type(16))) float f32x16;

__device__ __forceinline__ unsigned f2bf(float f) {          // RTNE float->bf16
    union { float f; unsigned u; } v; v.f = f;
    unsigned r = v.u + 0x7fffu + ((v.u >> 16) & 1u);
    return r >> 16;
}

// ---------------------------------------------------------------------------
// Fused: per block = one 256-t slab.
//  phase 1: z^T[64 d][256 t] = W(64x256) . x_slab(256x256) via MFMA 32x32x16,
//           bf16 operands, fp32 acc; +bias; ||z||^2 in fp32; z -> LDS bf16.
//  phase 2: scores = z(256x64) . cb^T(64x512) via MFMA; rmin fold; shfl min.
// LDS: cb 64K | W 32K | x-dbuf 32K (aliased by z after phase 1) | n2/zn/bias.
// ---------------------------------------------------------------------------
__global__ __launch_bounds__(512, 2) void fused_kernel(
    const float* __restrict__ x, const float* __restrict__ W,
    const float* __restrict__ bias, const float* __restrict__ cb,
    float* __restrict__ out)
{
    __shared__ char smem[134400];
    unsigned short* cbb = (unsigned short*)smem;             // [512][64] swz
    unsigned short* Wl  = (unsigned short*)(smem + 65536);   // [64][256] swz
    unsigned short* xsb = (unsigned short*)(smem + 98304);   // [2][32][256]
    unsigned short* zl  = (unsigned short*)(smem + 98304);   // [256][64] swz (alias)
    float* n2b = (float*)(smem + 131072);                    // [512]
    float* znb = (float*)(smem + 133120);                    // [256]
    float* bl  = (float*)(smem + 134144);                    // [64]

    const int tid  = threadIdx.x;
    const int bid  = blockIdx.x;
    const int b    = bid >> 5;
    const int t0   = (bid & 31) << 8;
    const int lane = tid & 63;
    const int l31  = lane & 31;
    const int lh   = lane >> 5;
    const int wid  = tid >> 6;

    const float* xb = x + (size_t)(b * CIN) * T_ + t0;

    // ---- stage codebook row n=tid (bf16, slot-swizzled) + n2  [verified code]
    {
        const float* cr = cb + (size_t)tid * 64;
        float s = 0.f;
        #pragma unroll
        for (int sl = 0; sl < 8; ++sl) {
            float4 a4 = *(const float4*)(cr + sl * 8);
            float4 b4 = *(const float4*)(cr + sl * 8 + 4);
            s = fmaf(a4.x, a4.x, s); s = fmaf(a4.y, a4.y, s);
            s = fmaf(a4.z, a4.z, s); s = fmaf(a4.w, a4.w, s);
            s = fmaf(b4.x, b4.x, s); s = fmaf(b4.y, b4.y, s);
            s = fmaf(b4.z, b4.z, s); s = fmaf(b4.w, b4.w, s);
            uint4 pk;
            pk.x = f2bf(a4.x) | (f2bf(a4.y) << 16);
            pk.y = f2bf(a4.z) | (f2bf(a4.w) << 16);
            pk.z = f2bf(b4.x) | (f2bf(b4.y) << 16);
            pk.w = f2bf(b4.z) | (f2bf(b4.w) << 16);
            ((uint4*)cbb)[tid * 8 + (sl ^ (tid & 7))] = pk;
        }
        n2b[tid] = s;
        if (tid < 64) bl[tid] = bias[tid];
    }

    // ---- stage W: thread d=tid>>3, c0=(tid&7)*32; 16B slots, phys = s^(d&7)
    {
        const int d  = tid >> 3;
        const int c0 = (tid & 7) * 32;
        const float* wr = W + (size_t)d * CIN + c0;
        #pragma unroll
        for (int q = 0; q < 4; ++q) {
            float4 a4 = *(const float4*)(wr + q * 8);
            float4 b4 = *(const float4*)(wr + q * 8 + 4);
            uint4 pk;
            pk.x = f2bf(a4.x) | (f2bf(a4.y) << 16);
            pk.y = f2bf(a4.z) | (f2bf(a4.w) << 16);
            pk.z = f2bf(b4.x) | (f2bf(b4.y) << 16);
            pk.w = f2bf(b4.z) | (f2bf(b4.w) << 16);
            const int s = (c0 >> 3) + q;
            ((uint4*)Wl)[d * 32 + (s ^ (d & 7))] = pk;
        }
    }

#define LOADX(dst, ch_) do {                                                  \
        _Pragma("unroll")                                                     \
        for (int p = 0; p < 4; ++p) {                                         \
            int id_ = p * 512 + tid;                                          \
            int cl_ = id_ >> 6;                                               \
            int tl_ = (id_ & 63) << 2;                                        \
            dst[p] = *(const float4*)(xb + (size_t)((ch_) * 32 + cl_) * T_ + tl_); \
        }                                                                     \
    } while (0)

#define WRITEX(src, bsel_) do {                                               \
        _Pragma("unroll")                                                     \
        for (int p = 0; p < 4; ++p) {                                         \
            int id_ = p * 512 + tid;                                          \
            int cl_ = id_ >> 6;                                               \
            int tl_ = (id_ & 63) << 2;                                        \
            uint2 pk_;                                                        \
            pk_.x = f2bf(src[p].x) | (f2bf(src[p].y) << 16);                  \
            pk_.y = f2bf(src[p].z) | (f2bf(src[p].w) << 16);                  \
            *(uint2*)(xsb + (bsel_) * 8192 + (cl_ << 8) + tl_) = pk_;         \
        }                                                                     \
    } while (0)

    float4 st[4];
    LOADX(st, 0);
    WRITEX(st, 0);
    __syncthreads();

    // ---- phase 1: 8 chunks of 32 c; wave: dtile = wid>>2, ttiles tt0,tt0+1
    const int dtile = wid >> 2;
    const int tt0   = (wid & 3) * 2;

    f32x16 acc0 = (f32x16)(0.0f), acc1 = (f32x16)(0.0f);

    #pragma unroll 1
    for (int ch = 0; ch < 8; ++ch) {
        if (ch + 1 < 8) LOADX(st, ch + 1);
        const unsigned short* xr = xsb + (ch & 1) * 8192;
        #pragma unroll
        for (int k2 = 0; k2 < 2; ++k2) {
            // A-frag: W[d=dtile*32+l31][c = (ch*2+k2)*16 + lh*8 .. +8]
            const int d = dtile * 32 + l31;
            const int s = (ch * 2 + k2) * 2 + lh;
            uint4 wv = ((const uint4*)Wl)[d * 32 + (s ^ (d & 7))];
            short8v wa = __builtin_bit_cast(short8v, wv);
            // B-frags: x[c_local = k2*16+lh*8+j][t = (tt0+q)*32+l31]
            #pragma unroll
            for (int q = 0; q < 2; ++q) {
                const int t  = (tt0 + q) * 32 + l31;
                const unsigned short* xp = xr + (k2 * 16 + lh * 8) * 256 + t;
                unsigned r0 = xp[0],    r1 = xp[256],  r2 = xp[512],  r3 = xp[768];
                unsigned r4 = xp[1024], r5 = xp[1280], r6 = xp[1536], r7 = xp[1792];
                uint4 bv;
                bv.x = r0 | (r1 << 16); bv.y = r2 | (r3 << 16);
                bv.z = r4 | (r5 << 16); bv.w = r6 | (r7 << 16);
                short8v xa = __builtin_bit_cast(short8v, bv);
                if (q == 0)
                    acc0 = __builtin_amdgcn_mfma_f32_32x32x16_bf16(wa, xa, acc0, 0, 0, 0);
                else
                    acc1 = __builtin_amdgcn_mfma_f32_32x32x16_bf16(wa, xa, acc1, 0, 0, 0);
            }
        }
        __syncthreads();
        if (ch + 1 < 8) WRITEX(st, (ch + 1) & 1);
        __syncthreads();
    }

    // ---- phase-1 epilogue: +bias, ||z||^2 (fp32), z -> zl (bf16, swizzled)
    float zsum[2];
    #pragma unroll
    for (int q = 0; q < 2; ++q) {
        f32x16& A = q ? acc1 : acc0;
        const int t = (tt0 + q) * 32 + l31;
        float ss = 0.f;
        #pragma unroll
        for (int r = 0; r < 16; ++r) {
            const int d = dtile * 32 + (r & 3) + 8 * (r >> 2) + 4 * lh;
            float v = A[r] + bl[d];
            A[r] = v;
            ss = fmaf(v, v, ss);
        }
        ss += __shfl_xor(ss, 32);        // partner lane: same t, other d-quads
        zsum[q] = ss;                    // this wave's dtile contribution (32 d)
        #pragma unroll
        for (int g = 0; g < 4; ++g) {
            const int dq = dtile * 32 + 8 * g + 4 * lh;   // 4 consecutive d
            uint2 pk;
            pk.x = f2bf(A[4 * g + 0]) | (f2bf(A[4 * g + 1]) << 16);
            pk.y = f2bf(A[4 * g + 2]) | (f2bf(A[4 * g + 3]) << 16);
            const int s    = dq >> 3;
            const int half = (dq >> 2) & 1;
            *(uint2*)((char*)zl + t * 128 + ((s ^ (t & 7)) << 4) + (half << 3)) = pk;
        }
    }
    if (dtile == 0 && lh == 0) {
        znb[(tt0 + 0) * 32 + l31] = zsum[0];
        znb[(tt0 + 1) * 32 + l31] = zsum[1];
    }
    __syncthreads();
    if (dtile == 1 && lh == 0) {
        znb[(tt0 + 0) * 32 + l31] += zsum[0];
        znb[(tt0 + 1) * 32 + l31] += zsum[1];
    }
    __syncthreads();

    // ---- phase 2: wave wid owns t-tile wid; all 512 k
    const int tt = wid;
    short8v az[4];
    #pragma unroll
    for (int ks = 0; ks < 4; ++ks) {
        const int t = tt * 32 + l31;
        const int s = ks * 2 + lh;
        uint4 v = *(const uint4*)((char*)zl + t * 128 + ((s ^ (t & 7)) << 4));
        az[ks] = __builtin_bit_cast(short8v, v);
    }

    float rmin[16];
    #pragma unroll
    for (int r = 0; r < 16; ++r) rmin[r] = 3.0e38f;

    #pragma unroll 1
    for (int nt = 0; nt < 16; ++nt) {
        const int n = nt * 32 + l31;
        const float n2v = n2b[n];
        short8v bfr[4];
        #pragma unroll
        for (int ks = 0; ks < 4; ++ks) {
            const int s = ks * 2 + lh;
            uint4 v = ((const uint4*)cbb)[n * 8 + (s ^ (n & 7))];
            bfr[ks] = __builtin_bit_cast(short8v, v);
        }
        f32x16 acc = (f32x16)(0.0f);
        acc = __builtin_amdgcn_mfma_f32_32x32x16_bf16(az[0], bfr[0], acc, 0, 0, 0);
        acc = __builtin_amdgcn_mfma_f32_32x32x16_bf16(az[1], bfr[1], acc, 0, 0, 0);
        acc = __builtin_amdgcn_mfma_f32_32x32x16_bf16(az[2], bfr[2], acc, 0, 0, 0);
        acc = __builtin_amdgcn_mfma_f32_32x32x16_bf16(az[3], bfr[3], acc, 0, 0, 0);
        #pragma unroll
        for (int r = 0; r < 16; ++r)
            rmin[r] = fminf(rmin[r], fmaf(-2.f, acc[r], n2v));
    }

    // ---- min over the 32 k-columns (butterfly within each 32-lane half)
    #pragma unroll
    for (int m = 1; m <= 16; m <<= 1) {
        #pragma unroll
        for (int r = 0; r < 16; ++r)
            rmin[r] = fminf(rmin[r], __shfl_xor(rmin[r], m));
    }

    if (l31 == 0) {
        #pragma unroll
        for (int r = 0; r < 16; ++r) {
            const int t = tt * 32 + (r & 3) + 8 * (r >> 2) + 4 * lh;
            float v = znb[t] + rmin[r];
            float2 o; o.x = v; o.y = v;
            *(float2*)(out + (size_t)((bid << 8) + t) * 2) = o;
        }
    }
#undef LOADX
#undef WRITEX
}

// ---------------------------------------------------------------------------
extern "C" void kernel_launch(void* const* d_in, const int* in_sizes, int n_in,
                              void* d_out, int out_size, void* d_ws, size_t ws_size,
                              hipStream_t stream) {
    const float* x    = (const float*)d_in[0];
    const float* W    = (const float*)d_in[1];
    const float* bias = (const float*)d_in[2];
    const float* cb   = (const float*)d_in[3];
    float* out = (float*)d_out;
    (void)d_ws; (void)ws_size;

    fused_kernel<<<512, 512, 0, stream>>>(x, W, bias, cb, out);
}